// Round 4
// baseline (260.709 us; speedup 1.0000x reference)
//
#include <hip/hip_runtime.h>
#include <hip/hip_bf16.h>

// EdgeDegreeEmbeddingNetwork: N=10000 atoms, K=32 neighbors, NB=64, C=128, L=3, H=64
// out (N,9,128) f32 = concat_l [ (sh_l*mask)^T @ MLP_l(concat[scalars,tgt,src]) ] / 10
//
// Round-4 structure: grid = 3 l-groups x ceil(N/4). Block = 512 thr / 8 waves,
// owns ONE l and 4 atoms; per-l weights (49KB) + biases staged once into LDS.
// Wave (a,h) = 16 edges of atom a. H^T = W^T @ X^T per layer (wave holds full
// channel dim), LN/silu in registers, wave-private Hb exchange, MFMA einsum.
// 2 __syncthreads per block.

typedef __attribute__((ext_vector_type(8))) short bf16x8;   // 8 bf16 / 4 VGPR
typedef __attribute__((ext_vector_type(4))) short bf16x4;
typedef __attribute__((ext_vector_type(4))) float f32x4;

__device__ __forceinline__ unsigned short f2bf(float f) {
  __hip_bfloat16 h = __float2bfloat16(f);
  return *reinterpret_cast<unsigned short*>(&h);
}

// ---------------- weight repack: f32 -> bf16 MFMA A-fragment order ----------------
// frag element e=lane*8+j <-> W[k = Ks*32 + (lane>>4)*8 + j][n = Nt*16 + (lane&15)]
// ws layout (ushort): W1F [l:3][4][6][512] @0 ; W2F [l:3][4][2][512] @36864 ;
//                     W3F [l:3][8][2][512] @49152 ; mask flag @ int offset 36864
__global__ __launch_bounds__(256) void prep_weights(
    const float* __restrict__ W1, const float* __restrict__ W2,
    const float* __restrict__ W3, unsigned short* __restrict__ wf) {
  int idx = blockIdx.x * 256 + threadIdx.x;
  if (idx >= 73728) return;
  float val;
  if (idx < 36864) {                       // W1: 192 x 64
    int l = idx / 12288, r = idx % 12288;
    int blk = r >> 9, e = r & 511;
    int Nt = blk / 6, Ks = blk % 6;
    int lane = e >> 3, j = e & 7;
    int k = Ks * 32 + (lane >> 4) * 8 + j;
    int nn = Nt * 16 + (lane & 15);
    val = W1[l * 192 * 64 + k * 64 + nn];
  } else if (idx < 49152) {                // W2: 64 x 64
    int t = idx - 36864;
    int l = t / 4096, r = t % 4096;
    int blk = r >> 9, e = r & 511;
    int Nt = blk >> 1, Ks = blk & 1;
    int lane = e >> 3, j = e & 7;
    int k = Ks * 32 + (lane >> 4) * 8 + j;
    int nn = Nt * 16 + (lane & 15);
    val = W2[l * 64 * 64 + k * 64 + nn];
  } else {                                 // W3: 64 x 128
    int t = idx - 49152;
    int l = t / 8192, r = t % 8192;
    int blk = r >> 9, e = r & 511;
    int Nt = blk >> 1, Ks = blk & 1;
    int lane = e >> 3, j = e & 7;
    int k = Ks * 32 + (lane >> 4) * 8 + j;
    int nn = Nt * 16 + (lane & 15);
    val = W3[l * 64 * 128 + k * 128 + nn];
  }
  wf[idx] = f2bf(val);
}

// ---------------- mask dtype sniffer: 0=int32, 1=bytes, 2=float32 ----------------
__global__ __launch_bounds__(256) void sniff_mask(const unsigned int* __restrict__ m,
                                                  int* __restrict__ flag) {
  __shared__ int cOther, cFloat;
  if (threadIdx.x == 0) { cOther = 0; cFloat = 0; }
  __syncthreads();
  int other = 0, flt = 0;
#pragma unroll
  for (int i = 0; i < 8; ++i) {
    unsigned int w = m[threadIdx.x * 8 + i];
    if (w == 0x3F800000u) flt++;
    else if (w > 1u) other++;
  }
  if (other) atomicAdd(&cOther, other);
  if (flt)   atomicAdd(&cFloat, flt);
  __syncthreads();
  if (threadIdx.x == 0) {
    int f;
    if (cOther == 0 && cFloat == 0) f = 0;
    else if (cFloat > cOther)       f = 2;
    else                            f = 1;
    *flag = f;
  }
}

__device__ __forceinline__ bf16x8 cvt8(float4 a, float4 b) {
  bf16x8 r;
  r[0] = (short)f2bf(a.x); r[1] = (short)f2bf(a.y);
  r[2] = (short)f2bf(a.z); r[3] = (short)f2bf(a.w);
  r[4] = (short)f2bf(b.x); r[5] = (short)f2bf(b.y);
  r[6] = (short)f2bf(b.z); r[7] = (short)f2bf(b.w);
  return r;
}

// In-register LN(+bias) + silu over 64 channels of one edge, spread across the
// 4 lanes {e, e+16, e+32, e+48}; bias/gamma/beta read from LDS (broadcast).
__device__ __forceinline__ void ln_silu_reg(
    const f32x4* acc, const float* bb, const float* gg, const float* be,
    unsigned short* HbW, int e, int g) {
  float v[16]; float s = 0.f, s2 = 0.f;
#pragma unroll
  for (int mt = 0; mt < 4; ++mt) {
    float4 b4 = *reinterpret_cast<const float4*>(bb + mt * 16 + 4 * g);
    const float* b4p = reinterpret_cast<const float*>(&b4);
#pragma unroll
    for (int i = 0; i < 4; ++i) {
      float x = acc[mt][i] + b4p[i];
      v[mt * 4 + i] = x; s += x; s2 += x * x;
    }
  }
  s  += __shfl_xor(s, 16);  s2 += __shfl_xor(s2, 16);
  s  += __shfl_xor(s, 32);  s2 += __shfl_xor(s2, 32);
  float mu  = s * 0.015625f;
  float var = s2 * 0.015625f - mu * mu;
  float rstd = rsqrtf(var + 1e-5f);
#pragma unroll
  for (int mt = 0; mt < 4; ++mt) {
    float4 g4 = *reinterpret_cast<const float4*>(gg + mt * 16 + 4 * g);
    float4 e4 = *reinterpret_cast<const float4*>(be + mt * 16 + 4 * g);
    const float* g4p = reinterpret_cast<const float*>(&g4);
    const float* e4p = reinterpret_cast<const float*>(&e4);
    bf16x4 pk;
#pragma unroll
    for (int i = 0; i < 4; ++i) {
      float y  = (v[mt * 4 + i] - mu) * rstd * g4p[i] + e4p[i];
      float sl = y * (1.0f / (1.0f + __expf(-y)));
      pk[i] = (short)f2bf(sl);
    }
    *reinterpret_cast<bf16x4*>(HbW + e * 72 + mt * 16 + 4 * g) = pk;  // b64 write
  }
}

#define MFMA __builtin_amdgcn_mfma_f32_16x16x32_bf16

__global__ __launch_bounds__(512, 2) void edge_net_kernel(
    const int*   __restrict__ an_arr,
    const float* __restrict__ edge_vec,
    const int*   __restrict__ f_idx,
    const void*  __restrict__ attn_mask,
    const float* __restrict__ edge_scalars,
    const float* __restrict__ src_emb,
    const float* __restrict__ tgt_emb,
    const float* __restrict__ b1, const float* __restrict__ g1, const float* __restrict__ be1,
    const float* __restrict__ b2, const float* __restrict__ g2, const float* __restrict__ be2,
    const float* __restrict__ b3,
    const unsigned short* __restrict__ wf,
    const int* __restrict__ mask_flag,
    float* __restrict__ out, int Nat) {

  __shared__ __align__(16) unsigned short WL[24576];        // this l's W1|W2|W3 frags, 48KB
  __shared__ __align__(16) float BL[512];                   // b1 g1 be1 b2 g2 be2 | b3
  __shared__ __align__(16) unsigned short Hb[8][16 * 72];   // wave-private, 18.4KB
  __shared__ __align__(16) unsigned short H3T[4][128 * 40]; // [atom][ch][k], 41KB
  __shared__ __align__(16) unsigned short shT[4][16 * 40];  // [atom][d][k], 5.1KB

  const int tid  = threadIdx.x;
  const int wave = tid >> 6, lane = tid & 63;
  const int e = lane & 15, g = lane >> 4;
  const int a = wave >> 1, h = wave & 1;
  const int chunk = blockIdx.x / 3;
  const int l = blockIdx.x - chunk * 3;
  int n = chunk * 4 + a;
  const bool valid = (n < Nat);
  if (!valid) n = Nat - 1;
  const int k = h * 16 + e;

  // ---- stage this l's weights + biases into LDS (linear copy) ----
  {
    const uint4* s1 = reinterpret_cast<const uint4*>(wf + l * 12288);
    const uint4* s2 = reinterpret_cast<const uint4*>(wf + 36864 + l * 4096);
    const uint4* s3 = reinterpret_cast<const uint4*>(wf + 49152 + l * 8192);
    uint4* dst = reinterpret_cast<uint4*>(WL);
#pragma unroll
    for (int it = 0; it < 6; ++it) {
      int i = it * 512 + tid;
      uint4 v;
      if (i < 1536)      v = s1[i];
      else if (i < 2048) v = s2[i - 1536];
      else               v = s3[i - 2048];
      dst[i] = v;
    }
    float bv;
    int t = tid >> 6, o = tid & 63;
    if (tid < 384) {
      const float* p = (t == 0) ? b1 : (t == 1) ? g1 : (t == 2) ? be1
                     : (t == 3) ? b2 : (t == 4) ? g2 : be2;
      bv = p[l * 64 + o];
    } else {
      bv = b3[l * 128 + (tid - 384)];
    }
    BL[tid] = bv;
  }

  // ---- phase 0: per-lane gathers, sh*mask -> shT, X -> 24 VGPRs ----
  const int an   = an_arr[n];
  const int srcA = an_arr[f_idx[n * 32 + k]];
  const int mflag = *mask_flag;
  bool masked;
  if (mflag == 0)      masked = ((const int*)attn_mask)[n * 32 + k] != 0;
  else if (mflag == 1) masked = ((const unsigned char*)attn_mask)[n * 32 + k] != 0;
  else                 masked = ((const float*)attn_mask)[n * 32 + k] != 0.0f;
  const float mf = masked ? 0.0f : 1.0f;

  {
    const float* ev = edge_vec + ((size_t)n * 32 + k) * 3;
    float ex = ev[0], ey = ev[1], ez = ev[2];
    float rn = rsqrtf(ex * ex + ey * ey + ez * ez);
    float x = ex * rn, y = ey * rn, z = ez * rn;
    const float s3c = 1.7320508075688772f;
    float s[9];
    s[0] = 1.f; s[1] = y; s[2] = z; s[3] = x;
    s[4] = s3c * x * y; s[5] = s3c * y * z; s[6] = 1.5f * z * z - 0.5f;
    s[7] = s3c * x * z; s[8] = 0.5f * s3c * (x * x - y * y);
    if (g < 3) {
#pragma unroll
      for (int q = 0; q < 3; ++q)
        shT[a][(g * 3 + q) * 40 + k] = f2bf(s[g * 3 + q] * mf);
    }
  }

  bf16x8 xf[6];   // X^T B-frags: lane(e,g) holds feats {ks*32 + g*8 + j} of edge k
  {
    const float* es = edge_scalars + ((size_t)n * 32 + k) * 64 + g * 8;
    const float4* p0 = reinterpret_cast<const float4*>(es);
    const float4* p1 = reinterpret_cast<const float4*>(es + 32);
    xf[0] = cvt8(p0[0], p0[1]);
    xf[1] = cvt8(p1[0], p1[1]);
    const float4* t0 = reinterpret_cast<const float4*>(tgt_emb + an * 64 + g * 8);
    const float4* t1 = reinterpret_cast<const float4*>(tgt_emb + an * 64 + 32 + g * 8);
    xf[2] = cvt8(t0[0], t0[1]);
    xf[3] = cvt8(t1[0], t1[1]);
    const float4* s0 = reinterpret_cast<const float4*>(src_emb + (size_t)srcA * 64 + g * 8);
    const float4* s1 = reinterpret_cast<const float4*>(src_emb + (size_t)srcA * 64 + 32 + g * 8);
    xf[4] = cvt8(s0[0], s0[1]);
    xf[5] = cvt8(s1[0], s1[1]);
  }

  __syncthreads();   // weights, biases, shT all resident

  unsigned short* HbW = &Hb[wave][0];
  const unsigned short* w1a = WL;            // frag (mt*6+ks)*512
  const unsigned short* w2a = WL + 12288;    // frag (mt*2+ks)*512
  const unsigned short* w3a = WL + 16384;    // frag (mt*2+ks)*512
  const float* b1l = BL;        const float* g1l = BL + 64;  const float* be1l = BL + 128;
  const float* b2l = BL + 192;  const float* g2l = BL + 256; const float* be2l = BL + 320;
  const float* b3l = BL + 384;

  // ---- L1: H1^T(64x16/wave) = W1^T @ X^T, K=192 ----
  f32x4 acc1[4];
#pragma unroll
  for (int mt = 0; mt < 4; ++mt) acc1[mt] = (f32x4){0.f, 0.f, 0.f, 0.f};
#pragma unroll
  for (int mt = 0; mt < 4; ++mt)
#pragma unroll
    for (int ks = 0; ks < 6; ++ks) {
      bf16x8 wfr = *reinterpret_cast<const bf16x8*>(w1a + ((mt * 6 + ks) << 9) + lane * 8);
      acc1[mt] = MFMA(wfr, xf[ks], acc1[mt], 0, 0, 0);
    }
  ln_silu_reg(acc1, b1l, g1l, be1l, HbW, e, g);
  asm volatile("s_waitcnt lgkmcnt(0)" ::: "memory");
  __builtin_amdgcn_sched_barrier(0);

  // ---- L2: K=64 ----
  bf16x8 hf[2];
#pragma unroll
  for (int ks = 0; ks < 2; ++ks)
    hf[ks] = *reinterpret_cast<const bf16x8*>(HbW + e * 72 + ks * 32 + g * 8);
  f32x4 acc2[4];
#pragma unroll
  for (int mt = 0; mt < 4; ++mt) acc2[mt] = (f32x4){0.f, 0.f, 0.f, 0.f};
#pragma unroll
  for (int mt = 0; mt < 4; ++mt)
#pragma unroll
    for (int ks = 0; ks < 2; ++ks) {
      bf16x8 wfr = *reinterpret_cast<const bf16x8*>(w2a + ((mt * 2 + ks) << 9) + lane * 8);
      acc2[mt] = MFMA(wfr, hf[ks], acc2[mt], 0, 0, 0);
    }
  ln_silu_reg(acc2, b2l, g2l, be2l, HbW, e, g);
  asm volatile("s_waitcnt lgkmcnt(0)" ::: "memory");
  __builtin_amdgcn_sched_barrier(0);

  // ---- L3: H3^T(128x16/wave) = W3^T @ H2^T, K=64; +bias -> H3T LDS ----
#pragma unroll
  for (int ks = 0; ks < 2; ++ks)
    hf[ks] = *reinterpret_cast<const bf16x8*>(HbW + e * 72 + ks * 32 + g * 8);
  f32x4 acc3[8];
#pragma unroll
  for (int mt = 0; mt < 8; ++mt) acc3[mt] = (f32x4){0.f, 0.f, 0.f, 0.f};
#pragma unroll
  for (int mt = 0; mt < 8; ++mt)
#pragma unroll
    for (int ks = 0; ks < 2; ++ks) {
      bf16x8 wfr = *reinterpret_cast<const bf16x8*>(w3a + ((mt * 2 + ks) << 9) + lane * 8);
      acc3[mt] = MFMA(wfr, hf[ks], acc3[mt], 0, 0, 0);
    }
#pragma unroll
  for (int mt = 0; mt < 8; ++mt) {
    float4 bb = *reinterpret_cast<const float4*>(b3l + mt * 16 + 4 * g);
    const float* bbp = reinterpret_cast<const float*>(&bb);
#pragma unroll
    for (int i = 0; i < 4; ++i)
      H3T[a][(mt * 16 + 4 * g + i) * 40 + k] = f2bf(acc3[mt][i] + bbp[i]);
  }
  __syncthreads();   // H3T complete across the atom's two waves

  // ---- einsum: D(16x128) = shT(A) @ H3T(B); store rows l^2 .. l^2+2l ----
  bf16x8 af = *reinterpret_cast<const bf16x8*>(&shT[a][(lane & 15) * 40 + g * 8]);
  const int lo = l * l, hi = l * l + 2 * l;
#pragma unroll
  for (int nt = 0; nt < 4; ++nt) {
    bf16x8 bfr = *reinterpret_cast<const bf16x8*>(
        &H3T[a][(h * 64 + nt * 16 + (lane & 15)) * 40 + g * 8]);
    f32x4 ez = (f32x4){0.f, 0.f, 0.f, 0.f};
    ez = MFMA(af, bfr, ez, 0, 0, 0);
#pragma unroll
    for (int i = 0; i < 4; ++i) {
      int d = 4 * g + i;
      if (valid && d >= lo && d <= hi)
        out[((size_t)n * 9 + d) * 128 + h * 64 + nt * 16 + (lane & 15)] = 0.1f * ez[i];
    }
  }
}

extern "C" void kernel_launch(void* const* d_in, const int* in_sizes, int n_in,
                              void* d_out, int out_size, void* d_ws, size_t ws_size,
                              hipStream_t stream) {
  const int*   atomic_numbers = (const int*)  d_in[0];
  const float* edge_vec       = (const float*)d_in[1];
  const int*   f_idx          = (const int*)  d_in[2];
  const void*  attn_mask      = d_in[3];
  const float* edge_scalars   = (const float*)d_in[4];
  const float* src_emb        = (const float*)d_in[5];
  const float* tgt_emb        = (const float*)d_in[6];
  const float* W1  = (const float*)d_in[7];
  const float* b1  = (const float*)d_in[8];
  const float* g1  = (const float*)d_in[9];
  const float* be1 = (const float*)d_in[10];
  const float* W2  = (const float*)d_in[11];
  const float* b2  = (const float*)d_in[12];
  const float* g2  = (const float*)d_in[13];
  const float* be2 = (const float*)d_in[14];
  const float* W3  = (const float*)d_in[15];
  const float* b3  = (const float*)d_in[16];

  unsigned short* wf = (unsigned short*)d_ws;
  int* mask_flag = ((int*)d_ws) + 36864;        // byte offset 147456
  float* out = (float*)d_out;
  const int N = in_sizes[0];

  prep_weights<<<288, 256, 0, stream>>>(W1, W2, W3, wf);
  sniff_mask<<<1, 256, 0, stream>>>((const unsigned int*)attn_mask, mask_flag);
  const int nblocks = ((N + 3) / 4) * 3;
  edge_net_kernel<<<nblocks, 512, 0, stream>>>(
      atomic_numbers, edge_vec, f_idx, attn_mask, edge_scalars,
      src_emb, tgt_emb, b1, g1, be1, b2, g2, be2, b3, wf, mask_flag, out, N);
}

// Round 5
// 214.274 us; speedup vs baseline: 1.2167x; 1.2167x over previous
//
#include <hip/hip_runtime.h>
#include <hip/hip_bf16.h>

// EdgeDegreeEmbeddingNetwork: N=10000 atoms, K=32 neighbors, NB=64, C=128, L=3, H=64
// out (N,9,128) f32 = concat_l [ (sh_l*mask)^T @ MLP_l(concat[scalars,tgt,src]) ] / 10
//
// Round-5: round-3 structure (2 atoms/block, 4 waves; wave (a,h) owns 16 edges
// of atom a; H^T = W^T @ X^T so LN/silu is in-register; wave-private Hb LDS
// exchange; MFMA einsum). Changes vs r3: approximate-rcp sigmoid (kills IEEE
// fdiv sequences), no inline-asm waitcnt/sched pins (compiler orders LDS deps
// and can overlap LN with next layer's weight loads), launch_bounds(256,5).

typedef __attribute__((ext_vector_type(8))) short bf16x8;   // 8 bf16 / 4 VGPR
typedef __attribute__((ext_vector_type(4))) short bf16x4;
typedef __attribute__((ext_vector_type(4))) float f32x4;

__device__ __forceinline__ unsigned short f2bf(float f) {
  __hip_bfloat16 h = __float2bfloat16(f);
  return *reinterpret_cast<unsigned short*>(&h);
}

// ---------------- weight repack: f32 -> bf16 MFMA A-fragment order ----------------
// frag element e=lane*8+j <-> W[k = Ks*32 + (lane>>4)*8 + j][n = Nt*16 + (lane&15)]
// ws layout (ushort): W1F [l:3][4][6][512] @0 ; W2F [l:3][4][2][512] @36864 ;
//                     W3F [l:3][8][2][512] @49152 ; mask flag @ int offset 36864
__global__ __launch_bounds__(256) void prep_weights(
    const float* __restrict__ W1, const float* __restrict__ W2,
    const float* __restrict__ W3, unsigned short* __restrict__ wf) {
  int idx = blockIdx.x * 256 + threadIdx.x;
  if (idx >= 73728) return;
  float val;
  if (idx < 36864) {                       // W1: 192 x 64
    int l = idx / 12288, r = idx % 12288;
    int blk = r >> 9, e = r & 511;
    int Nt = blk / 6, Ks = blk % 6;
    int lane = e >> 3, j = e & 7;
    int k = Ks * 32 + (lane >> 4) * 8 + j;
    int nn = Nt * 16 + (lane & 15);
    val = W1[l * 192 * 64 + k * 64 + nn];
  } else if (idx < 49152) {                // W2: 64 x 64
    int t = idx - 36864;
    int l = t / 4096, r = t % 4096;
    int blk = r >> 9, e = r & 511;
    int Nt = blk >> 1, Ks = blk & 1;
    int lane = e >> 3, j = e & 7;
    int k = Ks * 32 + (lane >> 4) * 8 + j;
    int nn = Nt * 16 + (lane & 15);
    val = W2[l * 64 * 64 + k * 64 + nn];
  } else {                                 // W3: 64 x 128
    int t = idx - 49152;
    int l = t / 8192, r = t % 8192;
    int blk = r >> 9, e = r & 511;
    int Nt = blk >> 1, Ks = blk & 1;
    int lane = e >> 3, j = e & 7;
    int k = Ks * 32 + (lane >> 4) * 8 + j;
    int nn = Nt * 16 + (lane & 15);
    val = W3[l * 64 * 128 + k * 128 + nn];
  }
  wf[idx] = f2bf(val);
}

// ---------------- mask dtype sniffer: 0=int32, 1=bytes, 2=float32 ----------------
__global__ __launch_bounds__(256) void sniff_mask(const unsigned int* __restrict__ m,
                                                  int* __restrict__ flag) {
  __shared__ int cOther, cFloat;
  if (threadIdx.x == 0) { cOther = 0; cFloat = 0; }
  __syncthreads();
  int other = 0, flt = 0;
#pragma unroll
  for (int i = 0; i < 8; ++i) {
    unsigned int w = m[threadIdx.x * 8 + i];
    if (w == 0x3F800000u) flt++;
    else if (w > 1u) other++;
  }
  if (other) atomicAdd(&cOther, other);
  if (flt)   atomicAdd(&cFloat, flt);
  __syncthreads();
  if (threadIdx.x == 0) {
    int f;
    if (cOther == 0 && cFloat == 0) f = 0;
    else if (cFloat > cOther)       f = 2;
    else                            f = 1;
    *flag = f;
  }
}

__device__ __forceinline__ bf16x8 cvt8(float4 a, float4 b) {
  bf16x8 r;
  r[0] = (short)f2bf(a.x); r[1] = (short)f2bf(a.y);
  r[2] = (short)f2bf(a.z); r[3] = (short)f2bf(a.w);
  r[4] = (short)f2bf(b.x); r[5] = (short)f2bf(b.y);
  r[6] = (short)f2bf(b.z); r[7] = (short)f2bf(b.w);
  return r;
}

// In-register LN(+bias) + silu over 64 channels of one edge, spread across the
// 4 lanes {e, e+16, e+32, e+48}; writes bf16 to wave-private Hb[e][ch] (pad 72).
__device__ __forceinline__ void ln_silu_reg(
    const f32x4* acc, const float* __restrict__ bb, const float* __restrict__ gg,
    const float* __restrict__ be, unsigned short* HbW, int e, int g) {
  float v[16]; float s = 0.f, s2 = 0.f;
#pragma unroll
  for (int mt = 0; mt < 4; ++mt) {
    float4 b4 = *reinterpret_cast<const float4*>(bb + mt * 16 + 4 * g);
    const float* b4p = reinterpret_cast<const float*>(&b4);
#pragma unroll
    for (int i = 0; i < 4; ++i) {
      float x = acc[mt][i] + b4p[i];
      v[mt * 4 + i] = x; s += x; s2 += x * x;
    }
  }
  s  += __shfl_xor(s, 16);  s2 += __shfl_xor(s2, 16);
  s  += __shfl_xor(s, 32);  s2 += __shfl_xor(s2, 32);
  float mu  = s * 0.015625f;
  float var = s2 * 0.015625f - mu * mu;
  float rstd = rsqrtf(var + 1e-5f);
#pragma unroll
  for (int mt = 0; mt < 4; ++mt) {
    float4 g4 = *reinterpret_cast<const float4*>(gg + mt * 16 + 4 * g);
    float4 e4 = *reinterpret_cast<const float4*>(be + mt * 16 + 4 * g);
    const float* g4p = reinterpret_cast<const float*>(&g4);
    const float* e4p = reinterpret_cast<const float*>(&e4);
    bf16x4 pk;
#pragma unroll
    for (int i = 0; i < 4; ++i) {
      float y  = (v[mt * 4 + i] - mu) * rstd * g4p[i] + e4p[i];
      // silu = y * sigmoid(y); approximate rcp (~2^-22) is far inside bf16 tol
      float sl = y * __builtin_amdgcn_rcpf(1.0f + __expf(-y));
      pk[i] = (short)f2bf(sl);
    }
    *reinterpret_cast<bf16x4*>(HbW + e * 72 + mt * 16 + 4 * g) = pk;  // b64 write
  }
}

#define MFMA __builtin_amdgcn_mfma_f32_16x16x32_bf16

__global__ __launch_bounds__(256, 5) void edge_net_kernel(
    const int*   __restrict__ an_arr,
    const float* __restrict__ edge_vec,
    const int*   __restrict__ f_idx,
    const void*  __restrict__ attn_mask,
    const float* __restrict__ edge_scalars,
    const float* __restrict__ src_emb,
    const float* __restrict__ tgt_emb,
    const float* __restrict__ b1, const float* __restrict__ g1, const float* __restrict__ be1,
    const float* __restrict__ b2, const float* __restrict__ g2, const float* __restrict__ be2,
    const float* __restrict__ b3,
    const unsigned short* __restrict__ wf,
    const int* __restrict__ mask_flag,
    float* __restrict__ out, int Nat) {

  __shared__ __align__(16) unsigned short Hb[4][16 * 72];    // wave-private, 9.2 KB
  __shared__ __align__(16) unsigned short H3T[2][128 * 40];  // [atom][ch][k] 20.5 KB
  __shared__ __align__(16) unsigned short shT[2][16 * 40];   // [atom][d][k]  2.5 KB

  const int tid  = threadIdx.x;
  const int wave = tid >> 6, lane = tid & 63;
  const int e = lane & 15, g = lane >> 4;
  const int a = wave >> 1, h = wave & 1;
  int n = blockIdx.x * 2 + a;
  const bool valid = (n < Nat);
  if (!valid) n = Nat - 1;
  const int k = h * 16 + e;

  // ---- phase 0: per-lane gathers, sh*mask -> shT, X -> 24 VGPRs ----
  const int an   = an_arr[n];
  const int srcA = an_arr[f_idx[n * 32 + k]];
  const int mflag = *mask_flag;
  bool masked;
  if (mflag == 0)      masked = ((const int*)attn_mask)[n * 32 + k] != 0;
  else if (mflag == 1) masked = ((const unsigned char*)attn_mask)[n * 32 + k] != 0;
  else                 masked = ((const float*)attn_mask)[n * 32 + k] != 0.0f;
  const float mf = masked ? 0.0f : 1.0f;

  {
    const float* ev = edge_vec + ((size_t)n * 32 + k) * 3;
    float ex = ev[0], ey = ev[1], ez = ev[2];
    float rn = rsqrtf(ex * ex + ey * ey + ez * ez);
    float x = ex * rn, y = ey * rn, z = ez * rn;
    const float s3 = 1.7320508075688772f;
    float s[9];
    s[0] = 1.f; s[1] = y; s[2] = z; s[3] = x;
    s[4] = s3 * x * y; s[5] = s3 * y * z; s[6] = 1.5f * z * z - 0.5f;
    s[7] = s3 * x * z; s[8] = 0.5f * s3 * (x * x - y * y);
    if (g < 3) {
#pragma unroll
      for (int q = 0; q < 3; ++q)
        shT[a][(g * 3 + q) * 40 + k] = f2bf(s[g * 3 + q] * mf);
    }
  }

  bf16x8 xf[6];   // X^T B-frags: lane(e,g) holds feats {ks*32 + g*8 + j} of edge k
  {
    const float* es = edge_scalars + ((size_t)n * 32 + k) * 64 + g * 8;
    const float4* p0 = reinterpret_cast<const float4*>(es);
    const float4* p1 = reinterpret_cast<const float4*>(es + 32);
    xf[0] = cvt8(p0[0], p0[1]);
    xf[1] = cvt8(p1[0], p1[1]);
    const float4* t0 = reinterpret_cast<const float4*>(tgt_emb + an * 64 + g * 8);
    const float4* t1 = reinterpret_cast<const float4*>(tgt_emb + an * 64 + 32 + g * 8);
    xf[2] = cvt8(t0[0], t0[1]);
    xf[3] = cvt8(t1[0], t1[1]);
    const float4* s0 = reinterpret_cast<const float4*>(src_emb + (size_t)srcA * 64 + g * 8);
    const float4* s1 = reinterpret_cast<const float4*>(src_emb + (size_t)srcA * 64 + 32 + g * 8);
    xf[4] = cvt8(s0[0], s0[1]);
    xf[5] = cvt8(s1[0], s1[1]);
  }

  unsigned short* HbW = &Hb[wave][0];

  for (int l = 0; l < 3; ++l) {
    const unsigned short* w1a = wf + l * 12288;
    const unsigned short* w2a = wf + 36864 + l * 4096;
    const unsigned short* w3a = wf + 49152 + l * 8192;

    __syncthreads();   // previous einsum reads of H3T done before we rewrite it

    // ---- L1: H1^T(64x16/wave) = W1^T @ X^T, K=192 ----
    f32x4 acc1[4];
#pragma unroll
    for (int mt = 0; mt < 4; ++mt) acc1[mt] = (f32x4){0.f, 0.f, 0.f, 0.f};
#pragma unroll
    for (int mt = 0; mt < 4; ++mt)
#pragma unroll
      for (int ks = 0; ks < 6; ++ks) {
        bf16x8 wfr = *reinterpret_cast<const bf16x8*>(w1a + ((mt * 6 + ks) << 9) + lane * 8);
        acc1[mt] = MFMA(wfr, xf[ks], acc1[mt], 0, 0, 0);
      }
    ln_silu_reg(acc1, b1 + l * 64, g1 + l * 64, be1 + l * 64, HbW, e, g);

    // ---- L2: K=64 ----
    bf16x8 hf[2];
#pragma unroll
    for (int ks = 0; ks < 2; ++ks)
      hf[ks] = *reinterpret_cast<const bf16x8*>(HbW + e * 72 + ks * 32 + g * 8);
    f32x4 acc2[4];
#pragma unroll
    for (int mt = 0; mt < 4; ++mt) acc2[mt] = (f32x4){0.f, 0.f, 0.f, 0.f};
#pragma unroll
    for (int mt = 0; mt < 4; ++mt)
#pragma unroll
      for (int ks = 0; ks < 2; ++ks) {
        bf16x8 wfr = *reinterpret_cast<const bf16x8*>(w2a + ((mt * 2 + ks) << 9) + lane * 8);
        acc2[mt] = MFMA(wfr, hf[ks], acc2[mt], 0, 0, 0);
      }
    ln_silu_reg(acc2, b2 + l * 64, g2 + l * 64, be2 + l * 64, HbW, e, g);

    // ---- L3: H3^T(128x16/wave) = W3^T @ H2^T, K=64; +bias -> H3T LDS ----
#pragma unroll
    for (int ks = 0; ks < 2; ++ks)
      hf[ks] = *reinterpret_cast<const bf16x8*>(HbW + e * 72 + ks * 32 + g * 8);
    f32x4 acc3[8];
#pragma unroll
    for (int mt = 0; mt < 8; ++mt) acc3[mt] = (f32x4){0.f, 0.f, 0.f, 0.f};
#pragma unroll
    for (int mt = 0; mt < 8; ++mt)
#pragma unroll
      for (int ks = 0; ks < 2; ++ks) {
        bf16x8 wfr = *reinterpret_cast<const bf16x8*>(w3a + ((mt * 2 + ks) << 9) + lane * 8);
        acc3[mt] = MFMA(wfr, hf[ks], acc3[mt], 0, 0, 0);
      }
#pragma unroll
    for (int mt = 0; mt < 8; ++mt) {
      float4 bb = *reinterpret_cast<const float4*>(b3 + l * 128 + mt * 16 + 4 * g);
      const float* bbp = reinterpret_cast<const float*>(&bb);
#pragma unroll
      for (int i = 0; i < 4; ++i)
        H3T[a][(mt * 16 + 4 * g + i) * 40 + k] = f2bf(acc3[mt][i] + bbp[i]);
    }
    __syncthreads();   // H3T complete across the atom's two waves

    // ---- einsum: D(16x128) = shT(A) @ H3T(B); store rows l^2 .. l^2+2l ----
    bf16x8 af = *reinterpret_cast<const bf16x8*>(&shT[a][(lane & 15) * 40 + g * 8]);
    const int lo = l * l, hi = l * l + 2 * l;
#pragma unroll
    for (int nt = 0; nt < 4; ++nt) {
      bf16x8 bfr = *reinterpret_cast<const bf16x8*>(
          &H3T[a][(h * 64 + nt * 16 + (lane & 15)) * 40 + g * 8]);
      f32x4 ez = (f32x4){0.f, 0.f, 0.f, 0.f};
      ez = MFMA(af, bfr, ez, 0, 0, 0);
#pragma unroll
      for (int i = 0; i < 4; ++i) {
        int d = 4 * g + i;
        if (valid && d >= lo && d <= hi)
          out[((size_t)n * 9 + d) * 128 + h * 64 + nt * 16 + (lane & 15)] = 0.1f * ez[i];
      }
    }
  }
}

extern "C" void kernel_launch(void* const* d_in, const int* in_sizes, int n_in,
                              void* d_out, int out_size, void* d_ws, size_t ws_size,
                              hipStream_t stream) {
  const int*   atomic_numbers = (const int*)  d_in[0];
  const float* edge_vec       = (const float*)d_in[1];
  const int*   f_idx          = (const int*)  d_in[2];
  const void*  attn_mask      = d_in[3];
  const float* edge_scalars   = (const float*)d_in[4];
  const float* src_emb        = (const float*)d_in[5];
  const float* tgt_emb        = (const float*)d_in[6];
  const float* W1  = (const float*)d_in[7];
  const float* b1  = (const float*)d_in[8];
  const float* g1  = (const float*)d_in[9];
  const float* be1 = (const float*)d_in[10];
  const float* W2  = (const float*)d_in[11];
  const float* b2  = (const float*)d_in[12];
  const float* g2  = (const float*)d_in[13];
  const float* be2 = (const float*)d_in[14];
  const float* W3  = (const float*)d_in[15];
  const float* b3  = (const float*)d_in[16];

  unsigned short* wf = (unsigned short*)d_ws;
  int* mask_flag = ((int*)d_ws) + 36864;        // byte offset 147456
  float* out = (float*)d_out;
  const int N = in_sizes[0];

  prep_weights<<<288, 256, 0, stream>>>(W1, W2, W3, wf);
  sniff_mask<<<1, 256, 0, stream>>>((const unsigned int*)attn_mask, mask_flag);
  edge_net_kernel<<<(N + 1) / 2, 256, 0, stream>>>(
      atomic_numbers, edge_vec, f_idx, attn_mask, edge_scalars,
      src_emb, tgt_emb, b1, g1, be1, b2, g2, be2, b3, wf, mask_flag, out, N);
}

// Round 6
// 185.202 us; speedup vs baseline: 1.4077x; 1.1570x over previous
//
#include <hip/hip_runtime.h>
#include <hip/hip_bf16.h>

// EdgeDegreeEmbeddingNetwork: N=10000 atoms, K=32 neighbors, NB=64, C=128, L=3, H=64
// out (N,9,128) f32 = concat_l [ (sh_l*mask)^T @ MLP_l(concat[scalars,tgt,src]) ] / 10
//
// Round-6: ZERO-BARRIER design. One wave = one atom (32 edges = 2 N-tiles).
// Block 256 = 4 independent waves/atoms. All inter-phase exchange is
// wave-private LDS (compiler orders via lgkmcnt; no __syncthreads anywhere).
// Hb (32x72) and H3T (128x40) time-share one union buffer U per wave.
// Einsum accumulates across l into persistent accE[8] via MFMA with per-lane
// zero-masked shB fragment (disjoint d-columns per l); single final store.

typedef __attribute__((ext_vector_type(8))) short bf16x8;   // 8 bf16 / 4 VGPR
typedef __attribute__((ext_vector_type(4))) short bf16x4;
typedef __attribute__((ext_vector_type(4))) float f32x4;

__device__ __forceinline__ unsigned short f2bf(float f) {
  __hip_bfloat16 h = __float2bfloat16(f);
  return *reinterpret_cast<unsigned short*>(&h);
}

// ---------------- weight repack: f32 -> bf16 MFMA A-fragment order ----------------
// frag element e=lane*8+j <-> W[k = Ks*32 + (lane>>4)*8 + j][n = Nt*16 + (lane&15)]
// ws layout (ushort): W1F [l:3][4][6][512] @0 ; W2F [l:3][4][2][512] @36864 ;
//                     W3F [l:3][8][2][512] @49152 ; mask flag @ int offset 36864
__global__ __launch_bounds__(256) void prep_weights(
    const float* __restrict__ W1, const float* __restrict__ W2,
    const float* __restrict__ W3, unsigned short* __restrict__ wf) {
  int idx = blockIdx.x * 256 + threadIdx.x;
  if (idx >= 73728) return;
  float val;
  if (idx < 36864) {                       // W1: 192 x 64
    int l = idx / 12288, r = idx % 12288;
    int blk = r >> 9, e = r & 511;
    int Nt = blk / 6, Ks = blk % 6;
    int lane = e >> 3, j = e & 7;
    int k = Ks * 32 + (lane >> 4) * 8 + j;
    int nn = Nt * 16 + (lane & 15);
    val = W1[l * 192 * 64 + k * 64 + nn];
  } else if (idx < 49152) {                // W2: 64 x 64
    int t = idx - 36864;
    int l = t / 4096, r = t % 4096;
    int blk = r >> 9, e = r & 511;
    int Nt = blk >> 1, Ks = blk & 1;
    int lane = e >> 3, j = e & 7;
    int k = Ks * 32 + (lane >> 4) * 8 + j;
    int nn = Nt * 16 + (lane & 15);
    val = W2[l * 64 * 64 + k * 64 + nn];
  } else {                                 // W3: 64 x 128
    int t = idx - 49152;
    int l = t / 8192, r = t % 8192;
    int blk = r >> 9, e = r & 511;
    int Nt = blk >> 1, Ks = blk & 1;
    int lane = e >> 3, j = e & 7;
    int k = Ks * 32 + (lane >> 4) * 8 + j;
    int nn = Nt * 16 + (lane & 15);
    val = W3[l * 64 * 128 + k * 128 + nn];
  }
  wf[idx] = f2bf(val);
}

// ---------------- mask dtype sniffer: 0=int32, 1=bytes, 2=float32 ----------------
__global__ __launch_bounds__(256) void sniff_mask(const unsigned int* __restrict__ m,
                                                  int* __restrict__ flag) {
  __shared__ int cOther, cFloat;
  if (threadIdx.x == 0) { cOther = 0; cFloat = 0; }
  __syncthreads();
  int other = 0, flt = 0;
#pragma unroll
  for (int i = 0; i < 8; ++i) {
    unsigned int w = m[threadIdx.x * 8 + i];
    if (w == 0x3F800000u) flt++;
    else if (w > 1u) other++;
  }
  if (other) atomicAdd(&cOther, other);
  if (flt)   atomicAdd(&cFloat, flt);
  __syncthreads();
  if (threadIdx.x == 0) {
    int f;
    if (cOther == 0 && cFloat == 0) f = 0;
    else if (cFloat > cOther)       f = 2;
    else                            f = 1;
    *flag = f;
  }
}

__device__ __forceinline__ bf16x8 cvt8(float4 a, float4 b) {
  bf16x8 r;
  r[0] = (short)f2bf(a.x); r[1] = (short)f2bf(a.y);
  r[2] = (short)f2bf(a.z); r[3] = (short)f2bf(a.w);
  r[4] = (short)f2bf(b.x); r[5] = (short)f2bf(b.y);
  r[6] = (short)f2bf(b.z); r[7] = (short)f2bf(b.w);
  return r;
}

// In-register LN(+bias)+silu for TWO edges (nt=0,1) of one lane; 64 ch spread
// across lanes {e, e+16, e+32, e+48}. Writes bf16 to wave union buffer Hb view
// (row stride 72 ushort = 144 B).
__device__ __forceinline__ void ln2(
    const f32x4 (&acc)[4][2], const float* __restrict__ bb,
    const float* __restrict__ gg, const float* __restrict__ be,
    unsigned short* Uw, int e, int g) {
  float v0[16], v1[16];
  float s0 = 0.f, s20 = 0.f, s1 = 0.f, s21 = 0.f;
#pragma unroll
  for (int mt = 0; mt < 4; ++mt) {
    float4 b4 = *reinterpret_cast<const float4*>(bb + mt * 16 + 4 * g);
    const float* b4p = reinterpret_cast<const float*>(&b4);
#pragma unroll
    for (int i = 0; i < 4; ++i) {
      float x0 = acc[mt][0][i] + b4p[i];
      float x1 = acc[mt][1][i] + b4p[i];
      v0[mt * 4 + i] = x0; s0 += x0; s20 += x0 * x0;
      v1[mt * 4 + i] = x1; s1 += x1; s21 += x1 * x1;
    }
  }
  s0 += __shfl_xor(s0, 16); s20 += __shfl_xor(s20, 16);
  s1 += __shfl_xor(s1, 16); s21 += __shfl_xor(s21, 16);
  s0 += __shfl_xor(s0, 32); s20 += __shfl_xor(s20, 32);
  s1 += __shfl_xor(s1, 32); s21 += __shfl_xor(s21, 32);
  float mu0 = s0 * 0.015625f, mu1 = s1 * 0.015625f;
  float r0 = rsqrtf(s20 * 0.015625f - mu0 * mu0 + 1e-5f);
  float r1 = rsqrtf(s21 * 0.015625f - mu1 * mu1 + 1e-5f);
#pragma unroll
  for (int mt = 0; mt < 4; ++mt) {
    float4 g4 = *reinterpret_cast<const float4*>(gg + mt * 16 + 4 * g);
    float4 e4 = *reinterpret_cast<const float4*>(be + mt * 16 + 4 * g);
    const float* g4p = reinterpret_cast<const float*>(&g4);
    const float* e4p = reinterpret_cast<const float*>(&e4);
    bf16x4 pk0, pk1;
#pragma unroll
    for (int i = 0; i < 4; ++i) {
      float y0 = (v0[mt * 4 + i] - mu0) * r0 * g4p[i] + e4p[i];
      float y1 = (v1[mt * 4 + i] - mu1) * r1 * g4p[i] + e4p[i];
      pk0[i] = (short)f2bf(y0 * __builtin_amdgcn_rcpf(1.0f + __expf(-y0)));
      pk1[i] = (short)f2bf(y1 * __builtin_amdgcn_rcpf(1.0f + __expf(-y1)));
    }
    *reinterpret_cast<bf16x4*>(Uw + e * 72 + mt * 16 + 4 * g) = pk0;
    *reinterpret_cast<bf16x4*>(Uw + (16 + e) * 72 + mt * 16 + 4 * g) = pk1;
  }
}

#define MFMA __builtin_amdgcn_mfma_f32_16x16x32_bf16

__global__ __launch_bounds__(256, 3) void edge_net_kernel(
    const int*   __restrict__ an_arr,
    const float* __restrict__ edge_vec,
    const int*   __restrict__ f_idx,
    const void*  __restrict__ attn_mask,
    const float* __restrict__ edge_scalars,
    const float* __restrict__ src_emb,
    const float* __restrict__ tgt_emb,
    const float* __restrict__ b1, const float* __restrict__ g1, const float* __restrict__ be1,
    const float* __restrict__ b2, const float* __restrict__ g2, const float* __restrict__ be2,
    const float* __restrict__ b3,
    const unsigned short* __restrict__ wf,
    const int* __restrict__ mask_flag,
    float* __restrict__ out, int Nat) {

  // Per wave: U[0..5119] = Hb view (32 rows x stride 72) / H3T view (128 rows x
  // stride 40), time-shared; U[5120..5759] = shB (16 d-rows x stride 40).
  __shared__ __align__(16) unsigned short U[4][5760];   // 46 KB total

  const int tid  = threadIdx.x;
  const int wave = tid >> 6, lane = tid & 63;
  const int e = lane & 15, g = lane >> 4;
  int n = blockIdx.x * 4 + wave;
  const bool valid = (n < Nat);
  if (!valid) n = Nat - 1;

  unsigned short* Uw  = &U[wave][0];
  unsigned short* shB = Uw + 5120;

  // ---- zero shB (rows 9..15 must be 0; cols of masked edges overwritten) ----
#pragma unroll
  for (int t = 0; t < 10; ++t) shB[t * 64 + lane] = 0;

  // ---- sh * mask -> shB (lanes g<2 each own one edge) ----
  const int mflag = *mask_flag;
  if (g < 2) {
    int k = g * 16 + e;
    bool masked;
    if (mflag == 0)      masked = ((const int*)attn_mask)[n * 32 + k] != 0;
    else if (mflag == 1) masked = ((const unsigned char*)attn_mask)[n * 32 + k] != 0;
    else                 masked = ((const float*)attn_mask)[n * 32 + k] != 0.0f;
    const float mf = masked ? 0.0f : 1.0f;
    const float* ev = edge_vec + ((size_t)n * 32 + k) * 3;
    float ex = ev[0], ey = ev[1], ez = ev[2];
    float rn = rsqrtf(ex * ex + ey * ey + ez * ez);
    float x = ex * rn, y = ey * rn, z = ez * rn;
    const float s3 = 1.7320508075688772f;
    float s[9];
    s[0] = 1.f; s[1] = y; s[2] = z; s[3] = x;
    s[4] = s3 * x * y; s[5] = s3 * y * z; s[6] = 1.5f * z * z - 0.5f;
    s[7] = s3 * x * z; s[8] = 0.5f * s3 * (x * x - y * y);
#pragma unroll
    for (int d = 0; d < 9; ++d) shB[d * 40 + k] = f2bf(s[d] * mf);
  }

  // ---- X^T B-frags in registers: xf[nt][ks], edge = nt*16+e, feats ks*32+g*8 ----
  const int an = an_arr[n];
  bf16x8 xf[2][6];
  {
    const float4* t0 = reinterpret_cast<const float4*>(tgt_emb + (size_t)an * 64 + g * 8);
    const float4* t1 = reinterpret_cast<const float4*>(tgt_emb + (size_t)an * 64 + 32 + g * 8);
    bf16x8 xt0 = cvt8(t0[0], t0[1]);
    bf16x8 xt1 = cvt8(t1[0], t1[1]);
#pragma unroll
    for (int nt = 0; nt < 2; ++nt) {
      int k = nt * 16 + e;
      const float* es = edge_scalars + ((size_t)n * 32 + k) * 64 + g * 8;
      const float4* p0 = reinterpret_cast<const float4*>(es);
      const float4* p1 = reinterpret_cast<const float4*>(es + 32);
      xf[nt][0] = cvt8(p0[0], p0[1]);
      xf[nt][1] = cvt8(p1[0], p1[1]);
      xf[nt][2] = xt0;
      xf[nt][3] = xt1;
      int srcA = an_arr[f_idx[n * 32 + k]];
      const float4* s0 = reinterpret_cast<const float4*>(src_emb + (size_t)srcA * 64 + g * 8);
      const float4* s1 = reinterpret_cast<const float4*>(src_emb + (size_t)srcA * 64 + 32 + g * 8);
      xf[nt][4] = cvt8(s0[0], s0[1]);
      xf[nt][5] = cvt8(s1[0], s1[1]);
    }
  }

  // einsum B-frag (all 9 d-rows; per-l column masking below)
  bf16x8 bfull = *reinterpret_cast<const bf16x8*>(shB + e * 40 + g * 8);

  f32x4 accE[8];
#pragma unroll
  for (int mt = 0; mt < 8; ++mt) accE[mt] = (f32x4){0.f, 0.f, 0.f, 0.f};

  for (int l = 0; l < 3; ++l) {
    const unsigned short* w1a = wf + l * 12288;
    const unsigned short* w2a = wf + 36864 + l * 4096;
    const unsigned short* w3a = wf + 49152 + l * 8192;

    // ---- L1: H1^T = W1^T @ X^T, K=192, M=64 (4 mt), N=32 (2 nt) ----
    f32x4 acc1[4][2];
#pragma unroll
    for (int mt = 0; mt < 4; ++mt)
#pragma unroll
      for (int nt = 0; nt < 2; ++nt) acc1[mt][nt] = (f32x4){0.f, 0.f, 0.f, 0.f};
#pragma unroll
    for (int mt = 0; mt < 4; ++mt)
#pragma unroll
      for (int ks = 0; ks < 6; ++ks) {
        bf16x8 wfr = *reinterpret_cast<const bf16x8*>(w1a + ((mt * 6 + ks) << 9) + lane * 8);
        acc1[mt][0] = MFMA(wfr, xf[0][ks], acc1[mt][0], 0, 0, 0);
        acc1[mt][1] = MFMA(wfr, xf[1][ks], acc1[mt][1], 0, 0, 0);
      }
    ln2(acc1, b1 + l * 64, g1 + l * 64, be1 + l * 64, Uw, e, g);

    // ---- L2: K=64 ----
    bf16x8 hf[2][2];
#pragma unroll
    for (int nt = 0; nt < 2; ++nt)
#pragma unroll
      for (int ks = 0; ks < 2; ++ks)
        hf[nt][ks] = *reinterpret_cast<const bf16x8*>(Uw + (nt * 16 + e) * 72 + ks * 32 + g * 8);
    f32x4 acc2[4][2];
#pragma unroll
    for (int mt = 0; mt < 4; ++mt)
#pragma unroll
      for (int nt = 0; nt < 2; ++nt) acc2[mt][nt] = (f32x4){0.f, 0.f, 0.f, 0.f};
#pragma unroll
    for (int mt = 0; mt < 4; ++mt)
#pragma unroll
      for (int ks = 0; ks < 2; ++ks) {
        bf16x8 wfr = *reinterpret_cast<const bf16x8*>(w2a + ((mt * 2 + ks) << 9) + lane * 8);
        acc2[mt][0] = MFMA(wfr, hf[0][ks], acc2[mt][0], 0, 0, 0);
        acc2[mt][1] = MFMA(wfr, hf[1][ks], acc2[mt][1], 0, 0, 0);
      }
    ln2(acc2, b2 + l * 64, g2 + l * 64, be2 + l * 64, Uw, e, g);

    // ---- L3: H3^T = W3^T @ H2^T, K=64, M=128 (8 mt); +bias -> H3T view of U ----
    // Load ALL H2 frags first (H3T writes overwrite the Hb region).
#pragma unroll
    for (int nt = 0; nt < 2; ++nt)
#pragma unroll
      for (int ks = 0; ks < 2; ++ks)
        hf[nt][ks] = *reinterpret_cast<const bf16x8*>(Uw + (nt * 16 + e) * 72 + ks * 32 + g * 8);
    const float* b3l = b3 + l * 128;
#pragma unroll
    for (int mt = 0; mt < 8; ++mt) {
      f32x4 a30 = (f32x4){0.f, 0.f, 0.f, 0.f};
      f32x4 a31 = (f32x4){0.f, 0.f, 0.f, 0.f};
#pragma unroll
      for (int ks = 0; ks < 2; ++ks) {
        bf16x8 wfr = *reinterpret_cast<const bf16x8*>(w3a + ((mt * 2 + ks) << 9) + lane * 8);
        a30 = MFMA(wfr, hf[0][ks], a30, 0, 0, 0);
        a31 = MFMA(wfr, hf[1][ks], a31, 0, 0, 0);
      }
      float4 bb = *reinterpret_cast<const float4*>(b3l + mt * 16 + 4 * g);
      const float* bbp = reinterpret_cast<const float*>(&bb);
#pragma unroll
      for (int i = 0; i < 4; ++i) {
        int row = (mt * 16 + 4 * g + i) * 40;
        Uw[row + e]      = f2bf(a30[i] + bbp[i]);
        Uw[row + 16 + e] = f2bf(a31[i] + bbp[i]);
      }
    }

    // ---- einsum: accE[mt] += H3T_tile(mt) @ shB (cols outside [lo,hi] zeroed) ----
    const int lo = l * l, hi = l * l + 2 * l;
    bf16x8 bfr = (e >= lo && e <= hi) ? bfull : (bf16x8)(short)0;
#pragma unroll
    for (int mt = 0; mt < 8; ++mt) {
      bf16x8 afr = *reinterpret_cast<const bf16x8*>(Uw + (mt * 16 + e) * 40 + g * 8);
      accE[mt] = MFMA(afr, bfr, accE[mt], 0, 0, 0);
    }
  }

  // ---- single final store: out[n][d=e][ch], ch = mt*16+4g+i ----
  if (valid && e < 9) {
    float* op = out + ((size_t)n * 9 + e) * 128;
#pragma unroll
    for (int mt = 0; mt < 8; ++mt) {
      float4 v;
      v.x = 0.1f * accE[mt][0]; v.y = 0.1f * accE[mt][1];
      v.z = 0.1f * accE[mt][2]; v.w = 0.1f * accE[mt][3];
      *reinterpret_cast<float4*>(op + mt * 16 + 4 * g) = v;
    }
  }
}

extern "C" void kernel_launch(void* const* d_in, const int* in_sizes, int n_in,
                              void* d_out, int out_size, void* d_ws, size_t ws_size,
                              hipStream_t stream) {
  const int*   atomic_numbers = (const int*)  d_in[0];
  const float* edge_vec       = (const float*)d_in[1];
  const int*   f_idx          = (const int*)  d_in[2];
  const void*  attn_mask      = d_in[3];
  const float* edge_scalars   = (const float*)d_in[4];
  const float* src_emb        = (const float*)d_in[5];
  const float* tgt_emb        = (const float*)d_in[6];
  const float* W1  = (const float*)d_in[7];
  const float* b1  = (const float*)d_in[8];
  const float* g1  = (const float*)d_in[9];
  const float* be1 = (const float*)d_in[10];
  const float* W2  = (const float*)d_in[11];
  const float* b2  = (const float*)d_in[12];
  const float* g2  = (const float*)d_in[13];
  const float* be2 = (const float*)d_in[14];
  const float* W3  = (const float*)d_in[15];
  const float* b3  = (const float*)d_in[16];

  unsigned short* wf = (unsigned short*)d_ws;
  int* mask_flag = ((int*)d_ws) + 36864;        // byte offset 147456
  float* out = (float*)d_out;
  const int N = in_sizes[0];

  prep_weights<<<288, 256, 0, stream>>>(W1, W2, W3, wf);
  sniff_mask<<<1, 256, 0, stream>>>((const unsigned int*)attn_mask, mask_flag);
  edge_net_kernel<<<(N + 3) / 4, 256, 0, stream>>>(
      atomic_numbers, edge_vec, f_idx, attn_mask, edge_scalars,
      src_emb, tgt_emb, b1, g1, be1, b2, g2, be2, b3, wf, mask_flag, out, N);
}

// Round 7
// 148.821 us; speedup vs baseline: 1.7518x; 1.2445x over previous
//
#include <hip/hip_runtime.h>
#include <hip/hip_bf16.h>

// EdgeDegreeEmbeddingNetwork: N=10000 atoms, K=32 neighbors, NB=64, C=128, L=3, H=64
// out (N,9,128) f32 = concat_l [ (sh_l*mask)^T @ MLP_l(concat[scalars,tgt,src]) ] / 10
//
// Round-7: r6 zero-barrier structure (one wave = one atom, 32 edges = 2 N-tiles,
// 4 independent waves/block, wave-private LDS only) with the LDS footprint
// HALVED: L3+einsum run in two 64-channel halves that time-share one 64x40
// H3T region, so U/wave = union(Hb 32x72, H3T 64x40) + shB = 3200 ushort.
// 25.6 KB/block -> 6 blocks/CU (24 waves/CU) vs r6's 3 (12 waves/CU).

typedef __attribute__((ext_vector_type(8))) short bf16x8;   // 8 bf16 / 4 VGPR
typedef __attribute__((ext_vector_type(4))) short bf16x4;
typedef __attribute__((ext_vector_type(4))) float f32x4;

__device__ __forceinline__ unsigned short f2bf(float f) {
  __hip_bfloat16 h = __float2bfloat16(f);
  return *reinterpret_cast<unsigned short*>(&h);
}

// ---------------- weight repack: f32 -> bf16 MFMA A-fragment order ----------------
// frag element e=lane*8+j <-> W[k = Ks*32 + (lane>>4)*8 + j][n = Nt*16 + (lane&15)]
// ws layout (ushort): W1F [l:3][4][6][512] @0 ; W2F [l:3][4][2][512] @36864 ;
//                     W3F [l:3][8][2][512] @49152 ; mask flag @ int offset 36864
__global__ __launch_bounds__(256) void prep_weights(
    const float* __restrict__ W1, const float* __restrict__ W2,
    const float* __restrict__ W3, unsigned short* __restrict__ wf) {
  int idx = blockIdx.x * 256 + threadIdx.x;
  if (idx >= 73728) return;
  float val;
  if (idx < 36864) {                       // W1: 192 x 64
    int l = idx / 12288, r = idx % 12288;
    int blk = r >> 9, e = r & 511;
    int Nt = blk / 6, Ks = blk % 6;
    int lane = e >> 3, j = e & 7;
    int k = Ks * 32 + (lane >> 4) * 8 + j;
    int nn = Nt * 16 + (lane & 15);
    val = W1[l * 192 * 64 + k * 64 + nn];
  } else if (idx < 49152) {                // W2: 64 x 64
    int t = idx - 36864;
    int l = t / 4096, r = t % 4096;
    int blk = r >> 9, e = r & 511;
    int Nt = blk >> 1, Ks = blk & 1;
    int lane = e >> 3, j = e & 7;
    int k = Ks * 32 + (lane >> 4) * 8 + j;
    int nn = Nt * 16 + (lane & 15);
    val = W2[l * 64 * 64 + k * 64 + nn];
  } else {                                 // W3: 64 x 128
    int t = idx - 49152;
    int l = t / 8192, r = t % 8192;
    int blk = r >> 9, e = r & 511;
    int Nt = blk >> 1, Ks = blk & 1;
    int lane = e >> 3, j = e & 7;
    int k = Ks * 32 + (lane >> 4) * 8 + j;
    int nn = Nt * 16 + (lane & 15);
    val = W3[l * 64 * 128 + k * 128 + nn];
  }
  wf[idx] = f2bf(val);
}

// ---------------- mask dtype sniffer: 0=int32, 1=bytes, 2=float32 ----------------
__global__ __launch_bounds__(256) void sniff_mask(const unsigned int* __restrict__ m,
                                                  int* __restrict__ flag) {
  __shared__ int cOther, cFloat;
  if (threadIdx.x == 0) { cOther = 0; cFloat = 0; }
  __syncthreads();
  int other = 0, flt = 0;
#pragma unroll
  for (int i = 0; i < 8; ++i) {
    unsigned int w = m[threadIdx.x * 8 + i];
    if (w == 0x3F800000u) flt++;
    else if (w > 1u) other++;
  }
  if (other) atomicAdd(&cOther, other);
  if (flt)   atomicAdd(&cFloat, flt);
  __syncthreads();
  if (threadIdx.x == 0) {
    int f;
    if (cOther == 0 && cFloat == 0) f = 0;
    else if (cFloat > cOther)       f = 2;
    else                            f = 1;
    *flag = f;
  }
}

__device__ __forceinline__ bf16x8 cvt8(float4 a, float4 b) {
  bf16x8 r;
  r[0] = (short)f2bf(a.x); r[1] = (short)f2bf(a.y);
  r[2] = (short)f2bf(a.z); r[3] = (short)f2bf(a.w);
  r[4] = (short)f2bf(b.x); r[5] = (short)f2bf(b.y);
  r[6] = (short)f2bf(b.z); r[7] = (short)f2bf(b.w);
  return r;
}

// In-register LN(+bias)+silu for TWO edges (nt=0,1) of one lane; 64 ch spread
// across lanes {e, e+16, e+32, e+48}. Writes bf16 to wave union buffer Hb view
// (row stride 72 ushort = 144 B).
__device__ __forceinline__ void ln2(
    const f32x4 (&acc)[4][2], const float* __restrict__ bb,
    const float* __restrict__ gg, const float* __restrict__ be,
    unsigned short* Uw, int e, int g) {
  float v0[16], v1[16];
  float s0 = 0.f, s20 = 0.f, s1 = 0.f, s21 = 0.f;
#pragma unroll
  for (int mt = 0; mt < 4; ++mt) {
    float4 b4 = *reinterpret_cast<const float4*>(bb + mt * 16 + 4 * g);
    const float* b4p = reinterpret_cast<const float*>(&b4);
#pragma unroll
    for (int i = 0; i < 4; ++i) {
      float x0 = acc[mt][0][i] + b4p[i];
      float x1 = acc[mt][1][i] + b4p[i];
      v0[mt * 4 + i] = x0; s0 += x0; s20 += x0 * x0;
      v1[mt * 4 + i] = x1; s1 += x1; s21 += x1 * x1;
    }
  }
  s0 += __shfl_xor(s0, 16); s20 += __shfl_xor(s20, 16);
  s1 += __shfl_xor(s1, 16); s21 += __shfl_xor(s21, 16);
  s0 += __shfl_xor(s0, 32); s20 += __shfl_xor(s20, 32);
  s1 += __shfl_xor(s1, 32); s21 += __shfl_xor(s21, 32);
  float mu0 = s0 * 0.015625f, mu1 = s1 * 0.015625f;
  float r0 = rsqrtf(s20 * 0.015625f - mu0 * mu0 + 1e-5f);
  float r1 = rsqrtf(s21 * 0.015625f - mu1 * mu1 + 1e-5f);
#pragma unroll
  for (int mt = 0; mt < 4; ++mt) {
    float4 g4 = *reinterpret_cast<const float4*>(gg + mt * 16 + 4 * g);
    float4 e4 = *reinterpret_cast<const float4*>(be + mt * 16 + 4 * g);
    const float* g4p = reinterpret_cast<const float*>(&g4);
    const float* e4p = reinterpret_cast<const float*>(&e4);
    bf16x4 pk0, pk1;
#pragma unroll
    for (int i = 0; i < 4; ++i) {
      float y0 = (v0[mt * 4 + i] - mu0) * r0 * g4p[i] + e4p[i];
      float y1 = (v1[mt * 4 + i] - mu1) * r1 * g4p[i] + e4p[i];
      pk0[i] = (short)f2bf(y0 * __builtin_amdgcn_rcpf(1.0f + __expf(-y0)));
      pk1[i] = (short)f2bf(y1 * __builtin_amdgcn_rcpf(1.0f + __expf(-y1)));
    }
    *reinterpret_cast<bf16x4*>(Uw + e * 72 + mt * 16 + 4 * g) = pk0;
    *reinterpret_cast<bf16x4*>(Uw + (16 + e) * 72 + mt * 16 + 4 * g) = pk1;
  }
}

#define MFMA __builtin_amdgcn_mfma_f32_16x16x32_bf16

__global__ __launch_bounds__(256, 3) void edge_net_kernel(
    const int*   __restrict__ an_arr,
    const float* __restrict__ edge_vec,
    const int*   __restrict__ f_idx,
    const void*  __restrict__ attn_mask,
    const float* __restrict__ edge_scalars,
    const float* __restrict__ src_emb,
    const float* __restrict__ tgt_emb,
    const float* __restrict__ b1, const float* __restrict__ g1, const float* __restrict__ be1,
    const float* __restrict__ b2, const float* __restrict__ g2, const float* __restrict__ be2,
    const float* __restrict__ b3,
    const unsigned short* __restrict__ wf,
    const int* __restrict__ mask_flag,
    float* __restrict__ out, int Nat) {

  // Per wave: U[0..2559] = Hb view (32 rows x stride 72, 2304 used) TIME-SHARED
  // with H3T-half view (64 rows x stride 40 = 2560); U[2560..3199] = shB
  // (16 d-rows x stride 40). 3200 ushort = 6.4 KB/wave -> 25.6 KB/block.
  __shared__ __align__(16) unsigned short U[4][3200];

  const int tid  = threadIdx.x;
  const int wave = tid >> 6, lane = tid & 63;
  const int e = lane & 15, g = lane >> 4;
  int n = blockIdx.x * 4 + wave;
  const bool valid = (n < Nat);
  if (!valid) n = Nat - 1;

  unsigned short* Uw  = &U[wave][0];
  unsigned short* shB = Uw + 2560;

  // ---- zero shB (rows 9..15 must be 0; cols of masked edges overwritten) ----
#pragma unroll
  for (int t = 0; t < 10; ++t) shB[t * 64 + lane] = 0;

  // ---- sh * mask -> shB (lanes g<2 each own one edge) ----
  const int mflag = *mask_flag;
  if (g < 2) {
    int k = g * 16 + e;
    bool masked;
    if (mflag == 0)      masked = ((const int*)attn_mask)[n * 32 + k] != 0;
    else if (mflag == 1) masked = ((const unsigned char*)attn_mask)[n * 32 + k] != 0;
    else                 masked = ((const float*)attn_mask)[n * 32 + k] != 0.0f;
    const float mf = masked ? 0.0f : 1.0f;
    const float* ev = edge_vec + ((size_t)n * 32 + k) * 3;
    float ex = ev[0], ey = ev[1], ez = ev[2];
    float rn = rsqrtf(ex * ex + ey * ey + ez * ez);
    float x = ex * rn, y = ey * rn, z = ez * rn;
    const float s3 = 1.7320508075688772f;
    float s[9];
    s[0] = 1.f; s[1] = y; s[2] = z; s[3] = x;
    s[4] = s3 * x * y; s[5] = s3 * y * z; s[6] = 1.5f * z * z - 0.5f;
    s[7] = s3 * x * z; s[8] = 0.5f * s3 * (x * x - y * y);
#pragma unroll
    for (int d = 0; d < 9; ++d) shB[d * 40 + k] = f2bf(s[d] * mf);
  }

  // ---- X^T B-frags in registers: xf[nt][ks], edge = nt*16+e, feats ks*32+g*8 ----
  const int an = an_arr[n];
  bf16x8 xf[2][6];
  {
    const float4* t0 = reinterpret_cast<const float4*>(tgt_emb + (size_t)an * 64 + g * 8);
    const float4* t1 = reinterpret_cast<const float4*>(tgt_emb + (size_t)an * 64 + 32 + g * 8);
    bf16x8 xt0 = cvt8(t0[0], t0[1]);
    bf16x8 xt1 = cvt8(t1[0], t1[1]);
#pragma unroll
    for (int nt = 0; nt < 2; ++nt) {
      int k = nt * 16 + e;
      const float* es = edge_scalars + ((size_t)n * 32 + k) * 64 + g * 8;
      const float4* p0 = reinterpret_cast<const float4*>(es);
      const float4* p1 = reinterpret_cast<const float4*>(es + 32);
      xf[nt][0] = cvt8(p0[0], p0[1]);
      xf[nt][1] = cvt8(p1[0], p1[1]);
      xf[nt][2] = xt0;
      xf[nt][3] = xt1;
      int srcA = an_arr[f_idx[n * 32 + k]];
      const float4* s0 = reinterpret_cast<const float4*>(src_emb + (size_t)srcA * 64 + g * 8);
      const float4* s1 = reinterpret_cast<const float4*>(src_emb + (size_t)srcA * 64 + 32 + g * 8);
      xf[nt][4] = cvt8(s0[0], s0[1]);
      xf[nt][5] = cvt8(s1[0], s1[1]);
    }
  }

  // einsum B-frag (all 9 d-rows; per-l column masking below)
  bf16x8 bfull = *reinterpret_cast<const bf16x8*>(shB + e * 40 + g * 8);

  f32x4 accE[8];
#pragma unroll
  for (int mt = 0; mt < 8; ++mt) accE[mt] = (f32x4){0.f, 0.f, 0.f, 0.f};

  for (int l = 0; l < 3; ++l) {
    const unsigned short* w1a = wf + l * 12288;
    const unsigned short* w2a = wf + 36864 + l * 4096;
    const unsigned short* w3a = wf + 49152 + l * 8192;

    // ---- L1: H1^T = W1^T @ X^T, K=192, M=64 (4 mt), N=32 (2 nt) ----
    f32x4 acc1[4][2];
#pragma unroll
    for (int mt = 0; mt < 4; ++mt)
#pragma unroll
      for (int nt = 0; nt < 2; ++nt) acc1[mt][nt] = (f32x4){0.f, 0.f, 0.f, 0.f};
#pragma unroll
    for (int mt = 0; mt < 4; ++mt)
#pragma unroll
      for (int ks = 0; ks < 6; ++ks) {
        bf16x8 wfr = *reinterpret_cast<const bf16x8*>(w1a + ((mt * 6 + ks) << 9) + lane * 8);
        acc1[mt][0] = MFMA(wfr, xf[0][ks], acc1[mt][0], 0, 0, 0);
        acc1[mt][1] = MFMA(wfr, xf[1][ks], acc1[mt][1], 0, 0, 0);
      }
    ln2(acc1, b1 + l * 64, g1 + l * 64, be1 + l * 64, Uw, e, g);

    // ---- L2: K=64 ----
    bf16x8 hf[2][2];
#pragma unroll
    for (int nt = 0; nt < 2; ++nt)
#pragma unroll
      for (int ks = 0; ks < 2; ++ks)
        hf[nt][ks] = *reinterpret_cast<const bf16x8*>(Uw + (nt * 16 + e) * 72 + ks * 32 + g * 8);
    f32x4 acc2[4][2];
#pragma unroll
    for (int mt = 0; mt < 4; ++mt)
#pragma unroll
      for (int nt = 0; nt < 2; ++nt) acc2[mt][nt] = (f32x4){0.f, 0.f, 0.f, 0.f};
#pragma unroll
    for (int mt = 0; mt < 4; ++mt)
#pragma unroll
      for (int ks = 0; ks < 2; ++ks) {
        bf16x8 wfr = *reinterpret_cast<const bf16x8*>(w2a + ((mt * 2 + ks) << 9) + lane * 8);
        acc2[mt][0] = MFMA(wfr, hf[0][ks], acc2[mt][0], 0, 0, 0);
        acc2[mt][1] = MFMA(wfr, hf[1][ks], acc2[mt][1], 0, 0, 0);
      }
    ln2(acc2, b2 + l * 64, g2 + l * 64, be2 + l * 64, Uw, e, g);

    // ---- L3 + einsum, in two 64-channel halves sharing one 64x40 H3T region ----
    // Load ALL H2 frags first (H3T writes overwrite the Hb region).
#pragma unroll
    for (int nt = 0; nt < 2; ++nt)
#pragma unroll
      for (int ks = 0; ks < 2; ++ks)
        hf[nt][ks] = *reinterpret_cast<const bf16x8*>(Uw + (nt * 16 + e) * 72 + ks * 32 + g * 8);
    const float* b3l = b3 + l * 128;
    const int lo = l * l, hi = l * l + 2 * l;
    bf16x8 bfr = (e >= lo && e <= hi) ? bfull : (bf16x8)(short)0;
#pragma unroll
    for (int half = 0; half < 2; ++half) {
#pragma unroll
      for (int mt = 0; mt < 4; ++mt) {
        const int mtg = half * 4 + mt;
        f32x4 a30 = (f32x4){0.f, 0.f, 0.f, 0.f};
        f32x4 a31 = (f32x4){0.f, 0.f, 0.f, 0.f};
#pragma unroll
        for (int ks = 0; ks < 2; ++ks) {
          bf16x8 wfr = *reinterpret_cast<const bf16x8*>(w3a + ((mtg * 2 + ks) << 9) + lane * 8);
          a30 = MFMA(wfr, hf[0][ks], a30, 0, 0, 0);
          a31 = MFMA(wfr, hf[1][ks], a31, 0, 0, 0);
        }
        float4 bb = *reinterpret_cast<const float4*>(b3l + mtg * 16 + 4 * g);
        const float* bbp = reinterpret_cast<const float*>(&bb);
#pragma unroll
        for (int i = 0; i < 4; ++i) {
          int row = (mt * 16 + 4 * g + i) * 40;
          Uw[row + e]      = f2bf(a30[i] + bbp[i]);
          Uw[row + 16 + e] = f2bf(a31[i] + bbp[i]);
        }
      }
      // einsum: accE[mtg] += H3T_half_tile(mt) @ shB (masked columns)
#pragma unroll
      for (int mt = 0; mt < 4; ++mt) {
        bf16x8 afr = *reinterpret_cast<const bf16x8*>(Uw + (mt * 16 + e) * 40 + g * 8);
        accE[half * 4 + mt] = MFMA(afr, bfr, accE[half * 4 + mt], 0, 0, 0);
      }
    }
  }

  // ---- single final store: out[n][d=e][ch], ch = mt*16+4g+i ----
  if (valid && e < 9) {
    float* op = out + ((size_t)n * 9 + e) * 128;
#pragma unroll
    for (int mt = 0; mt < 8; ++mt) {
      float4 v;
      v.x = 0.1f * accE[mt][0]; v.y = 0.1f * accE[mt][1];
      v.z = 0.1f * accE[mt][2]; v.w = 0.1f * accE[mt][3];
      *reinterpret_cast<float4*>(op + mt * 16 + 4 * g) = v;
    }
  }
}

extern "C" void kernel_launch(void* const* d_in, const int* in_sizes, int n_in,
                              void* d_out, int out_size, void* d_ws, size_t ws_size,
                              hipStream_t stream) {
  const int*   atomic_numbers = (const int*)  d_in[0];
  const float* edge_vec       = (const float*)d_in[1];
  const int*   f_idx          = (const int*)  d_in[2];
  const void*  attn_mask      = d_in[3];
  const float* edge_scalars   = (const float*)d_in[4];
  const float* src_emb        = (const float*)d_in[5];
  const float* tgt_emb        = (const float*)d_in[6];
  const float* W1  = (const float*)d_in[7];
  const float* b1  = (const float*)d_in[8];
  const float* g1  = (const float*)d_in[9];
  const float* be1 = (const float*)d_in[10];
  const float* W2  = (const float*)d_in[11];
  const float* b2  = (const float*)d_in[12];
  const float* g2  = (const float*)d_in[13];
  const float* be2 = (const float*)d_in[14];
  const float* W3  = (const float*)d_in[15];
  const float* b3  = (const float*)d_in[16];

  unsigned short* wf = (unsigned short*)d_ws;
  int* mask_flag = ((int*)d_ws) + 36864;        // byte offset 147456
  float* out = (float*)d_out;
  const int N = in_sizes[0];

  prep_weights<<<288, 256, 0, stream>>>(W1, W2, W3, wf);
  sniff_mask<<<1, 256, 0, stream>>>((const unsigned int*)attn_mask, mask_flag);
  edge_net_kernel<<<(N + 3) / 4, 256, 0, stream>>>(
      atomic_numbers, edge_vec, f_idx, attn_mask, edge_scalars,
      src_emb, tgt_emb, b1, g1, be1, b2, g2, be2, b3, wf, mask_flag, out, N);
}